// Round 3
// baseline (7827.926 us; speedup 1.0000x reference)
//
#include <hip/hip_runtime.h>

// Fused 3-layer tanh RNN (B=131072, T=6, V=31) + linear + tanh + softmax.
// R3: weights+biases staged in LDS once per block, packed as 64-float rows
// [wi(31) | bsum | wh(31) | pad] per output neuron. All 64 lanes read the
// same LDS address -> broadcast (free, no bank conflicts), read as
// ds_read_b128. This replaces R2's per-j global/scalar weight refetch
// (~35k latency-exposed fetches/thread -> 55% VALU idle, 8x inst bloat).
// State (h1..h3, xt) stays in VGPRs; __launch_bounds__(256,2) caps at 256
// VGPR (measured need ~200, no spill) giving 2 waves/SIMD.

#define VD 31
#define TD 6
#define LD 3
#define ROWF 64                    // floats per packed row
#define NROWS (LD * VD + VD)       // 93 RNN rows + 31 linear rows = 124
#define SMEMF (NROWS * ROWF)       // 7936 floats = 31 KB

__device__ __forceinline__ float fast_tanh(float x) {
    x = fminf(fmaxf(x, -15.0f), 15.0f);
    float e = __expf(2.0f * x);
    return (e - 1.0f) * __builtin_amdgcn_rcpf(e + 1.0f);
}

// One RNN layer step: hout[j] = tanh(bsum[j] + wi[j]·x + wh[j]·h)
// wbase points at this layer's 31 packed rows in LDS.
__device__ __forceinline__ void layer_step_lds(
    const float* __restrict__ wbase,
    const float (&x)[VD], const float (&hin)[VD], float (&hout)[VD])
{
#pragma unroll
    for (int j = 0; j < VD; ++j) {
        const float* w = wbase + j * ROWF;
        float acc_i = w[31];            // precombined bih+bhh
        float acc_h = 0.0f;
#pragma unroll
        for (int k = 0; k < VD; ++k) acc_i = fmaf(w[k], x[k], acc_i);
#pragma unroll
        for (int k = 0; k < VD; ++k) acc_h = fmaf(w[32 + k], hin[k], acc_h);
        hout[j] = fast_tanh(acc_i + acc_h);
    }
}

__global__ __launch_bounds__(256, 2) void rnn_fused(
    const float* __restrict__ inp,   // [B, T, V]
    const float* __restrict__ h0,    // [L, B, V]
    const float* __restrict__ Wih,   // [L, V, V]
    const float* __restrict__ Whh,   // [L, V, V]
    const float* __restrict__ bih,   // [L, V]
    const float* __restrict__ bhh,   // [L, V]
    const float* __restrict__ Wlin,  // [V, V]
    const float* __restrict__ blin,  // [V]
    float* __restrict__ out,         // [B, V]
    int B)
{
    __shared__ __align__(16) float smem[SMEMF];

    // ---- cooperative staging: pack weights + combined biases into LDS ----
    for (int idx = threadIdx.x; idx < SMEMF; idx += 256) {
        const int row = idx >> 6;       // /ROWF
        const int e   = idx & (ROWF - 1);
        float v = 0.0f;
        if (row < LD * VD) {
            const int l = row / VD;
            const int j = row - l * VD;
            if (e < VD)            v = Wih[(l * VD + j) * VD + e];
            else if (e == VD)      v = bih[l * VD + j] + bhh[l * VD + j];
            else if (e < 32 + VD)  v = Whh[(l * VD + j) * VD + (e - 32)];
        } else {
            const int j = row - LD * VD;
            if (e < VD)            v = Wlin[j * VD + e];
            else if (e == VD)      v = blin[j];
        }
        smem[idx] = v;
    }
    __syncthreads();

    const int b = blockIdx.x * blockDim.x + threadIdx.x;
    if (b >= B) return;

    float h1[VD], h2[VD], h3[VD];
    {
        const float* p0 = h0 + (size_t)b * VD;
        const float* p1 = h0 + ((size_t)B + b) * VD;
        const float* p2 = h0 + ((size_t)2 * B + b) * VD;
#pragma unroll
        for (int j = 0; j < VD; ++j) { h1[j] = p0[j]; h2[j] = p1[j]; h3[j] = p2[j]; }
    }

    const float* xb = inp + (size_t)b * TD * VD;
    const float* l0 = smem;
    const float* l1 = smem + VD * ROWF;
    const float* l2 = smem + 2 * VD * ROWF;
    const float* lf = smem + 3 * VD * ROWF;

    for (int t = 0; t < TD; ++t) {
        float xt[VD];
#pragma unroll
        for (int k = 0; k < VD; ++k) xt[k] = xb[t * VD + k];

        float tmp[VD];
        layer_step_lds(l0, xt, h1, tmp);
#pragma unroll
        for (int j = 0; j < VD; ++j) h1[j] = tmp[j];
        layer_step_lds(l1, h1, h2, tmp);
#pragma unroll
        for (int j = 0; j < VD; ++j) h2[j] = tmp[j];
        layer_step_lds(l2, h2, h3, tmp);
#pragma unroll
        for (int j = 0; j < VD; ++j) h3[j] = tmp[j];
    }

    // final linear + tanh
    float logits[VD];
#pragma unroll
    for (int j = 0; j < VD; ++j) {
        const float* w = lf + j * ROWF;
        float acc = w[31];              // blin
#pragma unroll
        for (int k = 0; k < VD; ++k) acc = fmaf(w[k], h3[k], acc);
        logits[j] = fast_tanh(acc);
    }

    // softmax over 31 logits
    float m = logits[0];
#pragma unroll
    for (int j = 1; j < VD; ++j) m = fmaxf(m, logits[j]);
    float e[VD];
    float s = 0.0f;
#pragma unroll
    for (int j = 0; j < VD; ++j) { e[j] = __expf(logits[j] - m); s += e[j]; }
    const float inv = __builtin_amdgcn_rcpf(s);
    float* ob = out + (size_t)b * VD;
#pragma unroll
    for (int j = 0; j < VD; ++j) ob[j] = e[j] * inv;
}

extern "C" void kernel_launch(void* const* d_in, const int* in_sizes, int n_in,
                              void* d_out, int out_size, void* d_ws, size_t ws_size,
                              hipStream_t stream) {
    const float* inp  = (const float*)d_in[0];
    const float* h0   = (const float*)d_in[1];
    const float* Wih  = (const float*)d_in[2];
    const float* Whh  = (const float*)d_in[3];
    const float* bih  = (const float*)d_in[4];
    const float* bhh  = (const float*)d_in[5];
    const float* Wlin = (const float*)d_in[6];
    const float* blin = (const float*)d_in[7];
    float* out = (float*)d_out;

    const int B = in_sizes[0] / (TD * VD);
    const int block = 256;
    const int grid = (B + block - 1) / block;
    rnn_fused<<<grid, block, 0, stream>>>(inp, h0, Wih, Whh, bih, bhh, Wlin, blin, out, B);
}